// Round 1
// baseline (430.492 us; speedup 1.0000x reference)
//
#include <hip/hip_runtime.h>
#include <hip/hip_fp16.h>

typedef _Float16 h2 __attribute__((ext_vector_type(2)));
typedef unsigned int u32;

#define B_TOTAL 262144
#define NBLK    512
#define SPB     512   // samples per block
#define ITERS   32    // SPB / 16

__device__ inline float fdot2f(h2 a, h2 b, float c) {
#if __has_builtin(__builtin_amdgcn_fdot2)
  return __builtin_amdgcn_fdot2(a, b, c, false);
#else
  return fmaf((float)a[0], (float)b[0], fmaf((float)a[1], (float)b[1], c));
#endif
}

// Fallback eigensolver (cyclic Jacobi) -- only taken if GE pivot < 1e-4 (never for this data).
__device__ __noinline__ void eig7_fallback(const float* Mg, float* det_o, float* lpos_o) {
  float a[49];
  for (int i = 0; i < 49; ++i) a[i] = Mg[i];
  for (int sw = 0; sw < 10; ++sw) {
    for (int p = 0; p < 6; ++p) {
      for (int q = p + 1; q < 7; ++q) {
        float apq = a[p*7+q];
        if (fabsf(apq) < 1e-12f) continue;
        float app = a[p*7+p], aqq = a[q*7+q];
        float th = 0.5f*(aqq - app)/apq;
        float tt = 1.0f/(fabsf(th) + sqrtf(th*th + 1.0f));
        if (th < 0.0f) tt = -tt;
        float cc = 1.0f/sqrtf(tt*tt + 1.0f), ss = tt*cc;
        for (int i = 0; i < 7; ++i) {
          float aip = a[i*7+p], aiq = a[i*7+q];
          a[i*7+p] = cc*aip - ss*aiq;
          a[i*7+q] = ss*aip + cc*aiq;
        }
        for (int i = 0; i < 7; ++i) {
          float api = a[p*7+i], aqi = a[q*7+i];
          a[p*7+i] = cc*api - ss*aqi;
          a[q*7+i] = ss*api + cc*aqi;
        }
      }
    }
  }
  float det = 1.0f, lp = 0.0f;
  for (int i = 0; i < 7; ++i) {
    float e = a[i*7+i];
    det *= e;
    float rl = fmaxf(1e-6f - e, 0.0f);
    lp += rl*rl;
  }
  *det_o = det;
  *lpos_o = lp * (1.0f/7.0f);
}

// Prep: pack Q = (W2 W2^T) o (W1^T W1) as f16 h-pairs, and W2 as f16 k-pairs, into ws.
__global__ void g2_prep(const float* __restrict__ W1, const float* __restrict__ W2,
                        u32* __restrict__ wsQ2, u32* __restrict__ wsW2) {
  int gid = blockIdx.x * 256 + threadIdx.x;
  if (gid < 8192) {
    int c = gid & 127, h2i = gid >> 7, h = 2*h2i;
    float mA = 0.f, mB = 0.f;
    for (int k = 0; k < 35; ++k) {
      float wc = W2[c*35 + k];
      mA = fmaf(W2[h*35 + k],     wc, mA);
      mB = fmaf(W2[(h+1)*35 + k], wc, mB);
    }
    float nA = 0.f, nB = 0.f;
    for (int j = 0; j < 7; ++j) {
      float wc = W1[j*128 + c];
      nA = fmaf(W1[j*128 + h],   wc, nA);
      nB = fmaf(W1[j*128 + h+1], wc, nB);
    }
    h2 q = {(_Float16)(mA*nA), (_Float16)(mB*nB)};
    wsQ2[gid] = __builtin_bit_cast(u32, q);
  } else if (gid < 8192 + 2304) {
    int i2 = gid - 8192;
    int hh = i2 / 18, k2 = i2 - hh*18;
    float w0 = W2[hh*35 + 2*k2];
    float w1 = (2*k2 + 1 < 35) ? W2[hh*35 + 2*k2 + 1] : 0.0f;
    h2 q = {(_Float16)w0, (_Float16)w1};
    wsW2[i2] = __builtin_bit_cast(u32, q);
  }
}

__global__ __launch_bounds__(256, 3) void g2_main(
    const float* __restrict__ coords, const float* __restrict__ metric,
    const float* __restrict__ W1, const float* __restrict__ b1,
    const float* __restrict__ b2,
    const u32* __restrict__ wsQ2, const u32* __restrict__ wsW2,
    float* __restrict__ partials)
{
  __shared__ __align__(16) h2 Q2[8192];      // [64 h-pairs][128 cols]
  __shared__ __align__(16) h2 W2k2[2304];    // [128 h][18 k-pairs]
  __shared__ h2 t2[16*66];                   // per-sample tanh pairs (padded stride 66)
  __shared__ h2 s2[16*66];                   // per-sample (1-t^2) pairs
  __shared__ h2 p2[16*20];                   // per-sample p k-pairs (18 used)
  __shared__ float red[256];

  const int tid = threadIdx.x;
  {
    const uint4* srcQ = (const uint4*)wsQ2;
    uint4* dstQ = (uint4*)Q2;
    #pragma unroll
    for (int i = 0; i < 8; ++i) dstQ[tid + 256*i] = srcQ[tid + 256*i];
    const uint4* srcW = (const uint4*)wsW2;
    uint4* dstW = (uint4*)W2k2;
    #pragma unroll
    for (int i = 0; i < 2; ++i) dstW[tid + 256*i] = srcW[tid + 256*i];
    if (tid < 64) dstW[512 + tid] = srcW[512 + tid];
  }
  __syncthreads();

  const int smp = tid >> 4;   // 0..15 local sample
  const int r   = tid & 15;   // lane within group; owns h = r + 16*i
  float acc_loss = 0.0f;

  for (int it = 0; it < ITERS; ++it) {
    const int sample = blockIdx.x * SPB + it * 16 + smp;

    // ---- phase A: det(metric) via unrolled GE (lane r==0) ----
    float det = 1.0f, lpos = 0.0f;
    if (r == 0) {
      const float* Mg = metric + (size_t)sample * 49;
      float m[49];
      #pragma unroll
      for (int i = 0; i < 49; ++i) m[i] = Mg[i];
      float minpiv = 3.4e38f;
      #pragma unroll
      for (int k = 0; k < 7; ++k) {
        float piv = m[k*7+k];
        minpiv = fminf(minpiv, piv);
        det *= piv;
        float inv = 1.0f / piv;
        #pragma unroll
        for (int i2 = k + 1; i2 < 7; ++i2) {
          float f = m[i2*7+k] * inv;
          #pragma unroll
          for (int j = k + 1; j < 7; ++j)
            m[i2*7+j] = fmaf(-f, m[k*7+j], m[i2*7+j]);
        }
      }
      if (!(minpiv > 1e-4f)) eig7_fallback(Mg, &det, &lpos);  // PD & accuracy fallback
    }

    // ---- phase B: z = W1^T c + b1, t = tanh, s = 1-t^2; pack pairs to LDS ----
    const float* cg = coords + (size_t)sample * 7;
    float c0 = cg[0], c1 = cg[1], c2 = cg[2], c3 = cg[3], c4 = cg[4], c5 = cg[5], c6 = cg[6];
    float s_own[8];
    #pragma unroll
    for (int i = 0; i < 8; ++i) {
      int h = r + 16*i;
      float z = b1[h];
      z = fmaf(c0, W1[      h], z);
      z = fmaf(c1, W1[128 + h], z);
      z = fmaf(c2, W1[256 + h], z);
      z = fmaf(c3, W1[384 + h], z);
      z = fmaf(c4, W1[512 + h], z);
      z = fmaf(c5, W1[640 + h], z);
      z = fmaf(c6, W1[768 + h], z);
      float ex = exp2f(z * 2.885390081777927f);   // e^{2z}
      float t  = 1.0f - 2.0f/(ex + 1.0f);         // tanh(z)
      float s  = fmaf(-t, t, 1.0f);
      s_own[i] = s;
      float tn = __shfl_xor(t, 1);
      float sn = __shfl_xor(s, 1);
      if ((r & 1) == 0) {
        int pi = (r >> 1) + 8*i;                  // pair index h/2
        h2 tv = {(_Float16)t, (_Float16)tn};
        h2 sv = {(_Float16)s, (_Float16)sn};
        t2[smp*66 + pi] = tv;
        s2[smp*66 + pi] = sv;
      }
    }
    __syncthreads();

    // ---- phase C: p = W2^T t + b2 (k-distributed: lane owns k-pair r, plus shared 16/17) ----
    float pe0 = b2[2*r], po0 = b2[2*r + 1];       // 2r+1 <= 31 < 35 always
    for (int x = 0; x < 64; ++x) {
      h2 tp = t2[smp*66 + x];
      float ta = (float)tp[0], tb = (float)tp[1];
      h2 wA = W2k2[(2*x)  *18 + r];
      h2 wB = W2k2[(2*x+1)*18 + r];
      pe0 = fmaf(ta, (float)wA[0], pe0);  po0 = fmaf(ta, (float)wA[1], po0);
      pe0 = fmaf(tb, (float)wB[0], pe0);  po0 = fmaf(tb, (float)wB[1], po0);
    }
    p2[smp*20 + r] = h2{(_Float16)pe0, (_Float16)po0};
    float n2p = pe0*pe0 + po0*po0;
    {
      // k-pairs 16,17 split across lanes: lanes 0-7 -> k2=16, lanes 8-15 -> k2=17
      int k2c = 16 + (r >> 3);
      int xs  = (r & 7) * 8;
      float pe1 = 0.f, po1 = 0.f;
      for (int dx = 0; dx < 8; ++dx) {
        int x = xs + dx;
        h2 tp = t2[smp*66 + x];
        float ta = (float)tp[0], tb = (float)tp[1];
        h2 wA = W2k2[(2*x)  *18 + k2c];
        h2 wB = W2k2[(2*x+1)*18 + k2c];
        pe1 = fmaf(ta, (float)wA[0], pe1);  po1 = fmaf(ta, (float)wA[1], po1);
        pe1 = fmaf(tb, (float)wB[0], pe1);  po1 = fmaf(tb, (float)wB[1], po1);
      }
      pe1 += __shfl_xor(pe1, 1);  po1 += __shfl_xor(po1, 1);
      pe1 += __shfl_xor(pe1, 2);  po1 += __shfl_xor(po1, 2);
      pe1 += __shfl_xor(pe1, 4);  po1 += __shfl_xor(po1, 4);
      if ((r & 7) == 0) {
        pe1 += b2[2*k2c];                          // k=32 or 34
        po1 += (k2c == 16) ? b2[33] : 0.0f;        // k=35 is pad
        p2[smp*20 + k2c] = h2{(_Float16)pe1, (_Float16)po1};
        n2p += pe1*pe1 + po1*po1;
      }
    }
    n2p += __shfl_xor(n2p, 1);
    n2p += __shfl_xor(n2p, 2);
    n2p += __shfl_xor(n2p, 4);
    n2p += __shfl_xor(n2p, 8);
    __syncthreads();

    // ---- phase D1: F2 = s^T Q s via f16 dot2 pairs ----
    float acc[8] = {0,0,0,0,0,0,0,0};
    for (int x = 0; x < 64; ++x) {
      h2 sv = s2[smp*66 + x];
      #pragma unroll
      for (int i = 0; i < 8; ++i)
        acc[i] = fdot2f(Q2[x*128 + r + 16*i], sv, acc[i]);
    }
    float F2 = 0.f;
    #pragma unroll
    for (int i = 0; i < 8; ++i) F2 = fmaf(s_own[i], acc[i], F2);
    F2 += __shfl_xor(F2, 1);
    F2 += __shfl_xor(F2, 2);
    F2 += __shfl_xor(F2, 4);
    F2 += __shfl_xor(F2, 8);

    // ---- phase D2: q = W2 p ; g = W1 (s o q) ; G2 = ||g||^2 ----
    h2 pv[18];
    #pragma unroll
    for (int k2 = 0; k2 < 18; ++k2) pv[k2] = p2[smp*20 + k2];
    float g[7] = {0,0,0,0,0,0,0};
    #pragma unroll
    for (int i = 0; i < 8; ++i) {
      int h = r + 16*i;
      float qv = 0.f;
      #pragma unroll
      for (int k2 = 0; k2 < 18; ++k2)
        qv = fdot2f(W2k2[h*18 + k2], pv[k2], qv);
      float sq = s_own[i] * qv;
      #pragma unroll
      for (int j = 0; j < 7; ++j)
        g[j] = fmaf(W1[j*128 + h], sq, g[j]);
    }
    #pragma unroll
    for (int j = 0; j < 7; ++j) {
      g[j] += __shfl_xor(g[j], 1);
      g[j] += __shfl_xor(g[j], 2);
      g[j] += __shfl_xor(g[j], 4);
      g[j] += __shfl_xor(g[j], 8);
    }

    // ---- phase E: per-sample loss (lane r==0) ----
    if (r == 0) {
      float G2 = 0.f;
      #pragma unroll
      for (int j = 0; j < 7; ++j) G2 = fmaf(g[j], g[j], G2);
      float n2 = n2p;
      float v  = sqrtf(fabsf(det) + 1e-10f);
      float nn = sqrtf(n2);
      float rr = fmaf(v, nn, 1e-8f);
      float a2 = 7.0f * (v*v) / (rr*rr);
      float be = v / (rr * nn);
      float fac = be * (2.0f - be * n2);
      float dual = a2 * (F2 - fac * G2);
      float dm1 = det - 1.0f;
      float nm7 = n2 - 7.0f;
      acc_loss += F2 + dual + dm1*dm1 + nm7*nm7 + lpos;
    }
    __syncthreads();
  }

  // ---- deterministic block reduction ----
  red[tid] = acc_loss;
  __syncthreads();
  #pragma unroll
  for (int sft = 128; sft > 0; sft >>= 1) {
    if (tid < sft) red[tid] += red[tid + sft];
    __syncthreads();
  }
  if (tid == 0) partials[blockIdx.x] = red[0];
}

__global__ void g2_finish(const float* __restrict__ partials, float* __restrict__ out) {
  __shared__ float red[256];
  int t = threadIdx.x;
  red[t] = partials[t] + partials[t + 256];
  __syncthreads();
  #pragma unroll
  for (int s = 128; s > 0; s >>= 1) {
    if (t < s) red[t] += red[t + s];
    __syncthreads();
  }
  if (t == 0) out[0] = red[0] * (1.0f / (float)B_TOTAL);
}

extern "C" void kernel_launch(void* const* d_in, const int* in_sizes, int n_in,
                              void* d_out, int out_size, void* d_ws, size_t ws_size,
                              hipStream_t stream) {
  const float* coords = (const float*)d_in[0];
  const float* metric = (const float*)d_in[1];
  const float* W1     = (const float*)d_in[2];
  const float* b1     = (const float*)d_in[3];
  const float* W2     = (const float*)d_in[4];
  const float* b2     = (const float*)d_in[5];
  float* out = (float*)d_out;

  u32* wsQ2 = (u32*)d_ws;               // 8192 u32
  u32* wsW2 = wsQ2 + 8192;              // 2304 u32
  float* partials = (float*)(wsW2 + 2304); // 512 f32

  g2_prep<<<41, 256, 0, stream>>>(W1, W2, wsQ2, wsW2);
  g2_main<<<NBLK, 256, 0, stream>>>(coords, metric, W1, b1, b2, wsQ2, wsW2, partials);
  g2_finish<<<1, 256, 0, stream>>>(partials, out);
}

// Round 4
// 252.312 us; speedup vs baseline: 1.7062x; 1.7062x over previous
//
#include <hip/hip_runtime.h>

typedef _Float16 f16;
typedef f16 f16x2 __attribute__((ext_vector_type(2)));
typedef f16 f16x8 __attribute__((ext_vector_type(8)));
typedef float f32x4 __attribute__((ext_vector_type(4)));
typedef unsigned int u32;
typedef u32 u32x2 __attribute__((ext_vector_type(2)));
typedef u32 u32x4 __attribute__((ext_vector_type(4)));

#define B_TOTAL 262144
#define NBLK    512
#define TPW     4      // 16-sample tiles per wave; 512 blk * 8 waves * 4 * 16 = 262144

// ---- ws / LDS layout (u32 indices) ----
#define OFF_QP   0       // Q  = (W2W2^T) o (W1^T W1): [128 rows][68 u32] (136-f16 padded rows)
#define OFF_M2P  8704    // M2 = W2W2^T: same layout
#define OFF_W1ZT 17408   // W1zT: [128 h][4 u32] f16 pairs j=0..7 (j==7 -> b1[h])
#define OFF_W1H  17920   // W1 padded: [16 j][68 u32] f16 pairs over h (j>=7 zero)
#define OFF_W2B  19008   // w2b = W2*b2: f32[128]
#define IDX_C2   19136   // ||b2||^2
#define NW_U32   19140

static __device__ inline u32 pkrtz(float a, float b) {
  auto r = __builtin_amdgcn_cvt_pkrtz(a, b);
  return __builtin_bit_cast(u32, r);
}
static __device__ inline float lo16f(u32 x) { f16x2 h = __builtin_bit_cast(f16x2, x); return (float)h[0]; }
static __device__ inline float hi16f(u32 x) { f16x2 h = __builtin_bit_cast(f16x2, x); return (float)h[1]; }
static __device__ inline f16x8 frag4(const u32 v[4]) {
  u32x4 t = { v[0], v[1], v[2], v[3] };
  return __builtin_bit_cast(f16x8, t);
}
static __device__ inline f32x4 mfma16(f16x8 a, f16x8 b, f32x4 c) {
  return __builtin_amdgcn_mfma_f32_16x16x32_f16(a, b, c, 0, 0, 0);
}
static __device__ inline float fdot2f(u32 a, u32 b, float c) {
  return __builtin_amdgcn_fdot2(__builtin_bit_cast(f16x2, a),
                                __builtin_bit_cast(f16x2, b), c, false);
}

// Jacobi fallback (only if a GE pivot is tiny -- never for this data distribution)
__device__ __noinline__ void eig7_fallback(const float* Mg, float* det_o, float* lpos_o) {
  float a[49];
  for (int i = 0; i < 49; ++i) a[i] = Mg[i];
  for (int sw = 0; sw < 10; ++sw)
    for (int p = 0; p < 6; ++p)
      for (int q = p + 1; q < 7; ++q) {
        float apq = a[p*7+q];
        if (fabsf(apq) < 1e-12f) continue;
        float th = 0.5f*(a[q*7+q] - a[p*7+p]) / apq;
        float tt = 1.0f/(fabsf(th) + sqrtf(th*th + 1.0f));
        if (th < 0.0f) tt = -tt;
        float cc = 1.0f/sqrtf(tt*tt + 1.0f), ss = tt*cc;
        for (int i = 0; i < 7; ++i) {
          float aip = a[i*7+p], aiq = a[i*7+q];
          a[i*7+p] = cc*aip - ss*aiq; a[i*7+q] = ss*aip + cc*aiq;
        }
        for (int i = 0; i < 7; ++i) {
          float api = a[p*7+i], aqi = a[q*7+i];
          a[p*7+i] = cc*api - ss*aqi; a[q*7+i] = ss*api + cc*aqi;
        }
      }
  float det = 1.0f, lp = 0.0f;
  for (int i = 0; i < 7; ++i) {
    float e = a[i*7+i];
    det *= e;
    float rl = fmaxf(1e-6f - e, 0.0f);
    lp += rl*rl;
  }
  *det_o = det; *lpos_o = lp * (1.0f/7.0f);
}

__global__ void g2_prep(const float* __restrict__ W1, const float* __restrict__ b1,
                        const float* __restrict__ W2, const float* __restrict__ b2,
                        u32* __restrict__ ws) {
  int gid = blockIdx.x * 256 + threadIdx.x;
  if (gid < 8192) {                         // QP + M2P pairs
    int h = gid >> 6, kp = gid & 63, k = 2 * kp;
    float m2a = 0.f, m2b = 0.f;
    for (int x = 0; x < 35; ++x) {
      float wh = W2[h*35 + x];
      m2a = fmaf(wh, W2[k*35 + x],     m2a);
      m2b = fmaf(wh, W2[(k+1)*35 + x], m2b);
    }
    float n1a = 0.f, n1b = 0.f;
    for (int j = 0; j < 7; ++j) {
      float wj = W1[j*128 + h];
      n1a = fmaf(wj, W1[j*128 + k],   n1a);
      n1b = fmaf(wj, W1[j*128 + k+1], n1b);
    }
    ws[OFF_QP  + h*68 + kp] = pkrtz(m2a*n1a, m2b*n1b);
    ws[OFF_M2P + h*68 + kp] = pkrtz(m2a, m2b);
  } else if (gid < 8704) {                  // W1zT: [h][jp]
    int idx = gid - 8192, h = idx >> 2, jp = idx & 3;
    int j0 = 2*jp, j1 = 2*jp + 1;
    float a = (j0 < 7) ? W1[j0*128 + h] : b1[h];
    float b = (j1 < 7) ? W1[j1*128 + h] : b1[h];
    ws[OFF_W1ZT + h*4 + jp] = pkrtz(a, b);
  } else if (gid < 9792) {                  // W1H: [j][kp] (j>=7 or pad -> 0)
    int idx = gid - 8704, j = idx / 68, kp = idx - j*68;
    float a = 0.f, b = 0.f;
    if (j < 7 && kp < 64) { a = W1[j*128 + 2*kp]; b = W1[j*128 + 2*kp + 1]; }
    ws[OFF_W1H + idx] = pkrtz(a, b);
  } else if (gid < 9920) {                  // w2b = W2 b2
    int h = gid - 9792;
    float s = 0.f;
    for (int x = 0; x < 35; ++x) s = fmaf(W2[h*35 + x], b2[x], s);
    ws[OFF_W2B + h] = __builtin_bit_cast(u32, s);
  } else if (gid == 9920) {                 // c2 = ||b2||^2
    float s = 0.f;
    for (int x = 0; x < 35; ++x) s = fmaf(b2[x], b2[x], s);
    ws[IDX_C2] = __builtin_bit_cast(u32, s);
  }
}

__global__ __launch_bounds__(512, 4) void g2_main(
    const float* __restrict__ coords, const float* __restrict__ metric,
    const u32* __restrict__ wsW, float* __restrict__ partials) {
  __shared__ __align__(16) u32 SMEM[NW_U32];
  const int tid = threadIdx.x;

  { // stage weights: 4785 uint4 = 19140 u32
    const u32x4* src = (const u32x4*)wsW;
    u32x4* dst = (u32x4*)SMEM;
    #pragma unroll
    for (int i = 0; i < 10; ++i) {
      int idx = tid + 512 * i;
      if (idx < 4785) dst[idx] = src[idx];
    }
  }
  __syncthreads();

  const int lane = tid & 63, wv = tid >> 6;
  const int g = lane >> 4, c = lane & 15;
  const int wave_gid = blockIdx.x * 8 + wv;
  const int sbase = wave_gid * 64;
  const char* LB = (const char*)SMEM;
  const float c2v = ((const float*)SMEM)[IDX_C2];

  // ---- dets for all 4 tiles up-front: lane L -> (tile L>>4, sample L&15) ----
  float detv = 1.f, lposv = 0.f;
  {
    const float* Mg = metric + (size_t)(sbase + lane) * 49;
    float m[49];
    #pragma unroll
    for (int i = 0; i < 49; ++i) m[i] = Mg[i];
    float minpiv = 3.4e38f;
    #pragma unroll
    for (int k = 0; k < 7; ++k) {
      float piv = m[k*8];
      minpiv = fminf(minpiv, piv);
      detv *= piv;
      float inv = 1.0f / piv;
      #pragma unroll
      for (int i2 = k + 1; i2 < 7; ++i2) {
        float f = m[i2*7 + k] * inv;
        #pragma unroll
        for (int j = k + 1; j < 7; ++j)
          m[i2*7 + j] = fmaf(-f, m[k*7 + j], m[i2*7 + j]);
      }
    }
    if (!(minpiv > 1e-4f)) eig7_fallback(Mg, &detv, &lposv);
  }

  float acc = 0.f;

  #pragma unroll 1
  for (int t = 0; t < TPW; ++t) {
    const int sb = sbase + t * 16;

    // ---- phase 1: z = W1^T c + b1 via MFMA; tanh; build s/t frags (lane-local) ----
    u32 bc[4] = {0,0,0,0};
    if (g < 2) {
      const float* cg = coords + (size_t)(sb + c) * 7 + 4*g;
      float f0 = cg[0], f1 = cg[1], f2 = cg[2];
      float f3 = (g == 0) ? cg[3] : 1.0f;     // j==7 slot multiplies the b1 row
      bc[0] = pkrtz(f0, f1); bc[1] = pkrtz(f2, f3);
    }
    const f16x8 bfrag = frag4(bc);

    u32 sf_[4][4], tf_[4][4];
    float w2t = 0.f;
    #pragma unroll
    for (int mt = 0; mt < 8; ++mt) {
      u32 az[4] = {0,0,0,0};
      if (g < 2) {
        u32x2 lo = *(const u32x2*)(LB + OFF_W1ZT*4 + (16*mt + c)*16 + 8*g);
        az[0] = lo.x; az[1] = lo.y;
      }
      f32x4 zz = mfma16(frag4(az), bfrag, f32x4{0.f,0.f,0.f,0.f});
      f32x4 wb = *(const f32x4*)(LB + OFF_W2B*4 + (16*mt + 4*g)*4);
      float tt[4], ss[4];
      #pragma unroll
      for (int r = 0; r < 4; ++r) {
        float ex = __builtin_amdgcn_exp2f(zz[r] * 2.8853900817779268f); // e^{2z}
        float rc = __builtin_amdgcn_rcpf(ex + 1.0f);
        float tv = fmaf(-2.0f, rc, 1.0f);
        tt[r] = tv; ss[r] = fmaf(-tv, tv, 1.0f);
        w2t = fmaf(tv, wb[r], w2t);
      }
      const int kk = mt >> 1, u0 = 2*(mt & 1);
      tf_[kk][u0]   = pkrtz(tt[0], tt[1]);
      tf_[kk][u0+1] = pkrtz(tt[2], tt[3]);
      sf_[kk][u0]   = pkrtz(ss[0], ss[1]);
      sf_[kk][u0+1] = pkrtz(ss[2], ss[3]);
    }

    // ---- phase 2: V = Q S^T (MFMA); F2 = s . V lane-locally ----
    float F2 = 0.f;
    #pragma unroll
    for (int mt = 0; mt < 8; ++mt) {
      const int row = c + 16*mt;
      f32x4 a = {0.f,0.f,0.f,0.f};
      #pragma unroll
      for (int kk = 0; kk < 4; ++kk) {
        const char* p = LB + (OFF_QP + row*68 + kk*16 + 2*g) * 4;
        u32x2 lo = *(const u32x2*)p;
        u32x2 hi = *(const u32x2*)(p + 32);
        u32 fr[4] = { lo.x, lo.y, hi.x, hi.y };
        a = mfma16(frag4(fr), frag4(sf_[kk]), a);
      }
      const int kk2 = mt >> 1, u0 = 2*(mt & 1);
      F2 = fdot2f(sf_[kk2][u0],   pkrtz(a[0], a[1]), F2);
      F2 = fdot2f(sf_[kk2][u0+1], pkrtz(a[2], a[3]), F2);
    }

    // ---- phase 3: V2 = M2 T^T; n2 diag; u = s o (V2 + w2b) (all lane-local) ----
    float n2d = 0.f;
    u32 upk[8][2];
    #pragma unroll
    for (int mt = 0; mt < 8; ++mt) {
      const int row = c + 16*mt;
      f32x4 a = {0.f,0.f,0.f,0.f};
      #pragma unroll
      for (int kk = 0; kk < 4; ++kk) {
        const char* p = LB + (OFF_M2P + row*68 + kk*16 + 2*g) * 4;
        u32x2 lo = *(const u32x2*)p;
        u32x2 hi = *(const u32x2*)(p + 32);
        u32 fr[4] = { lo.x, lo.y, hi.x, hi.y };
        a = mfma16(frag4(fr), frag4(tf_[kk]), a);
      }
      const int kk2 = mt >> 1, u0 = 2*(mt & 1);
      n2d = fdot2f(tf_[kk2][u0],   pkrtz(a[0], a[1]), n2d);
      n2d = fdot2f(tf_[kk2][u0+1], pkrtz(a[2], a[3]), n2d);
      f32x4 wb = *(const f32x4*)(LB + OFF_W2B*4 + (16*mt + 4*g)*4);
      float s0 = lo16f(sf_[kk2][u0]),   s1 = hi16f(sf_[kk2][u0]);
      float s2 = lo16f(sf_[kk2][u0+1]), s3 = hi16f(sf_[kk2][u0+1]);
      upk[mt][0] = pkrtz(s0*(a[0]+wb[0]), s1*(a[1]+wb[1]));
      upk[mt][1] = pkrtz(s2*(a[2]+wb[2]), s3*(a[3]+wb[3]));
    }

    // ---- phase 4: G = W1 * U^T via MFMA; G2 = sum_{j<7} G^2 ----
    f32x4 ga = {0.f,0.f,0.f,0.f};
    #pragma unroll
    for (int kk = 0; kk < 4; ++kk) {
      const char* p = LB + (OFF_W1H + c*68 + kk*16 + 2*g) * 4;
      u32x2 lo = *(const u32x2*)p;
      u32x2 hi = *(const u32x2*)(p + 32);
      u32 fr[4] = { lo.x, lo.y, hi.x, hi.y };
      u32 ub[4] = { upk[2*kk][0], upk[2*kk][1], upk[2*kk+1][0], upk[2*kk+1][1] };
      ga = mfma16(frag4(fr), frag4(ub), ga);
    }
    float p2g = 0.f;
    if (g == 0)      p2g = ga[0]*ga[0] + ga[1]*ga[1] + ga[2]*ga[2] + ga[3]*ga[3];
    else if (g == 1) p2g = ga[0]*ga[0] + ga[1]*ga[1] + ga[2]*ga[2];  // j = 4,5,6

    // ---- reductions over g-groups (columns fixed) ----
    F2  += __shfl_xor(F2, 16);  F2  += __shfl_xor(F2, 32);
    n2d += __shfl_xor(n2d, 16); n2d += __shfl_xor(n2d, 32);
    w2t += __shfl_xor(w2t, 16); w2t += __shfl_xor(w2t, 32);
    p2g += __shfl_xor(p2g, 16); p2g += __shfl_xor(p2g, 32);

    const float det  = __shfl(detv,  16*t + c);
    const float lpos = __shfl(lposv, 16*t + c);

    if (g == 0) {
      float n2 = n2d + 2.0f*w2t + c2v;
      float v  = sqrtf(fabsf(det) + 1e-10f);
      float nn = sqrtf(fmaxf(n2, 0.0f));
      float rr = fmaf(v, nn, 1e-8f);
      float a2 = 7.0f * v * v / (rr * rr);
      float be = v / (rr * nn + 1e-20f);
      float fac = be * (2.0f - be * n2);
      float dual = a2 * (F2 - fac * p2g);
      float dm1 = det - 1.0f, nm7 = n2 - 7.0f;
      acc += F2 + dual + dm1*dm1 + nm7*nm7 + lpos;
    }
    // w2t is re-zeroed next iteration via phase-1 recompute
  }

  // ---- block reduction (clobbers weight LDS; all waves done) ----
  __syncthreads();
  float* SFw = (float*)SMEM;
  SFw[tid] = acc;
  __syncthreads();
  #pragma unroll
  for (int s = 256; s > 0; s >>= 1) {
    if (tid < s) SFw[tid] += SFw[tid + s];
    __syncthreads();
  }
  if (tid == 0) partials[blockIdx.x] = SFw[0];
}

__global__ void g2_finish(const float* __restrict__ partials, float* __restrict__ out) {
  __shared__ float red[256];
  int t = threadIdx.x;
  red[t] = partials[t] + partials[t + 256];
  __syncthreads();
  #pragma unroll
  for (int s = 128; s > 0; s >>= 1) {
    if (t < s) red[t] += red[t + s];
    __syncthreads();
  }
  if (t == 0) out[0] = red[0] * (1.0f / (float)B_TOTAL);
}

extern "C" void kernel_launch(void* const* d_in, const int* in_sizes, int n_in,
                              void* d_out, int out_size, void* d_ws, size_t ws_size,
                              hipStream_t stream) {
  (void)in_sizes; (void)n_in; (void)out_size; (void)ws_size;
  const float* coords = (const float*)d_in[0];
  const float* metric = (const float*)d_in[1];
  const float* W1     = (const float*)d_in[2];
  const float* b1     = (const float*)d_in[3];
  const float* W2     = (const float*)d_in[4];
  const float* b2     = (const float*)d_in[5];
  float* out = (float*)d_out;

  u32* ws = (u32*)d_ws;
  float* partials = (float*)(ws + NW_U32);

  g2_prep<<<39, 256, 0, stream>>>(W1, b1, W2, b2, ws);
  g2_main<<<NBLK, 512, 0, stream>>>(coords, metric, ws, partials);
  g2_finish<<<1, 256, 0, stream>>>(partials, out);
}

// Round 5
// 59.040 us; speedup vs baseline: 7.2915x; 4.2736x over previous
//
#include <hip/hip_runtime.h>

typedef _Float16 f16;
typedef f16 f16x2 __attribute__((ext_vector_type(2)));
typedef f16 f16x8 __attribute__((ext_vector_type(8)));
typedef float f32x4 __attribute__((ext_vector_type(4)));
typedef unsigned int u32;
typedef u32 u32x2 __attribute__((ext_vector_type(2)));
typedef u32 u32x4 __attribute__((ext_vector_type(4)));

#define B_TOTAL 262144
#define NBLK    512
#define TPW     4      // 16-sample tiles per wave; 512 blk * 8 waves * 4 * 16 = 262144

// ---- ws / LDS layout (u32 indices) ----
#define OFF_QP   0       // Q  = (W2W2^T) o (W1^T W1): [128 rows][68 u32], frag-contiguous order
#define OFF_M2P  8704    // M2 = W2W2^T: same layout
#define OFF_W1ZT 17408   // W1zT: [128 h][4 u32] f16 pairs j=0..7 (j==7 -> b1[h])
#define OFF_W1H  17920   // W1 padded: [16 j][68 u32], frag-contiguous order (j>=7 zero)
#define OFF_W2B  19008   // w2b = W2*b2: f32[128]
#define IDX_C2   19136   // ||b2||^2
#define NW_U32   19140

static __device__ inline u32 pkrtz(float a, float b) {
  auto r = __builtin_amdgcn_cvt_pkrtz(a, b);
  return __builtin_bit_cast(u32, r);
}
static __device__ inline float lo16f(u32 x) { f16x2 h = __builtin_bit_cast(f16x2, x); return (float)h[0]; }
static __device__ inline float hi16f(u32 x) { f16x2 h = __builtin_bit_cast(f16x2, x); return (float)h[1]; }
static __device__ inline f16x8 frag4(const u32 v[4]) {
  u32x4 t = { v[0], v[1], v[2], v[3] };
  return __builtin_bit_cast(f16x8, t);
}
static __device__ inline f16x8 fragv(u32x4 v) { return __builtin_bit_cast(f16x8, v); }
static __device__ inline f32x4 mfma16(f16x8 a, f16x8 b, f32x4 c) {
  return __builtin_amdgcn_mfma_f32_16x16x32_f16(a, b, c, 0, 0, 0);
}
static __device__ inline float fdot2f(u32 a, u32 b, float c) {
  return __builtin_amdgcn_fdot2(__builtin_bit_cast(f16x2, a),
                                __builtin_bit_cast(f16x2, b), c, false);
}

// remap u32 offset within a 16-u32 kk block so each lane's 4 frag words are contiguous
static __device__ __host__ inline int frag_remap(int o) {
  return (o < 8) ? (4*(o >> 1) + (o & 1)) : (4*((o - 8) >> 1) + 2 + (o & 1));
}

// Jacobi fallback (only if a GE pivot is tiny -- never for this data distribution)
__device__ __noinline__ void eig7_fallback(const float* Mg, float* det_o, float* lpos_o) {
  float a[49];
  for (int i = 0; i < 49; ++i) a[i] = Mg[i];
  for (int sw = 0; sw < 10; ++sw)
    for (int p = 0; p < 6; ++p)
      for (int q = p + 1; q < 7; ++q) {
        float apq = a[p*7+q];
        if (fabsf(apq) < 1e-12f) continue;
        float th = 0.5f*(a[q*7+q] - a[p*7+p]) / apq;
        float tt = 1.0f/(fabsf(th) + sqrtf(th*th + 1.0f));
        if (th < 0.0f) tt = -tt;
        float cc = 1.0f/sqrtf(tt*tt + 1.0f), ss = tt*cc;
        for (int i = 0; i < 7; ++i) {
          float aip = a[i*7+p], aiq = a[i*7+q];
          a[i*7+p] = cc*aip - ss*aiq; a[i*7+q] = ss*aip + cc*aiq;
        }
        for (int i = 0; i < 7; ++i) {
          float api = a[p*7+i], aqi = a[q*7+i];
          a[p*7+i] = cc*api - ss*aqi; a[q*7+i] = ss*api + cc*aqi;
        }
      }
  float det = 1.0f, lp = 0.0f;
  for (int i = 0; i < 7; ++i) {
    float e = a[i*7+i];
    det *= e;
    float rl = fmaxf(1e-6f - e, 0.0f);
    lp += rl*rl;
  }
  *det_o = det; *lpos_o = lp * (1.0f/7.0f);
}

__global__ void g2_prep(const float* __restrict__ W1, const float* __restrict__ b1,
                        const float* __restrict__ W2, const float* __restrict__ b2,
                        u32* __restrict__ ws) {
  int gid = blockIdx.x * 256 + threadIdx.x;
  if (gid < 8192) {                         // QP + M2P pairs, frag-contiguous order
    int h = gid >> 6, kp = gid & 63, k = 2 * kp;
    float m2a = 0.f, m2b = 0.f;
    for (int x = 0; x < 35; ++x) {
      float wh = W2[h*35 + x];
      m2a = fmaf(wh, W2[k*35 + x],     m2a);
      m2b = fmaf(wh, W2[(k+1)*35 + x], m2b);
    }
    float n1a = 0.f, n1b = 0.f;
    for (int j = 0; j < 7; ++j) {
      float wj = W1[j*128 + h];
      n1a = fmaf(wj, W1[j*128 + k],   n1a);
      n1b = fmaf(wj, W1[j*128 + k+1], n1b);
    }
    int kk = kp >> 4, o = kp & 15;
    int kpn = kk*16 + frag_remap(o);
    ws[OFF_QP  + h*68 + kpn] = pkrtz(m2a*n1a, m2b*n1b);
    ws[OFF_M2P + h*68 + kpn] = pkrtz(m2a, m2b);
  } else if (gid < 8704) {                  // W1zT: [h][jp]
    int idx = gid - 8192, h = idx >> 2, jp = idx & 3;
    int j0 = 2*jp, j1 = 2*jp + 1;
    float a = (j0 < 7) ? W1[j0*128 + h] : b1[h];
    float b = (j1 < 7) ? W1[j1*128 + h] : b1[h];
    ws[OFF_W1ZT + h*4 + jp] = pkrtz(a, b);
  } else if (gid < 9792) {                  // W1H: [j][kp], frag-contiguous (j>=7 or pad -> 0)
    int idx = gid - 8704, j = idx / 68, kp = idx - j*68;
    float a = 0.f, b = 0.f;
    if (j < 7 && kp < 64) { a = W1[j*128 + 2*kp]; b = W1[j*128 + 2*kp + 1]; }
    int kpn = kp;
    if (kp < 64) { int kk = kp >> 4, o = kp & 15; kpn = kk*16 + frag_remap(o); }
    ws[OFF_W1H + j*68 + kpn] = pkrtz(a, b);
  } else if (gid < 9920) {                  // w2b = W2 b2
    int h = gid - 9792;
    float s = 0.f;
    for (int x = 0; x < 35; ++x) s = fmaf(W2[h*35 + x], b2[x], s);
    ws[OFF_W2B + h] = __builtin_bit_cast(u32, s);
  } else if (gid == 9920) {                 // c2 = ||b2||^2
    float s = 0.f;
    for (int x = 0; x < 35; ++x) s = fmaf(b2[x], b2[x], s);
    ws[IDX_C2] = __builtin_bit_cast(u32, s);
  }
}

__global__ __launch_bounds__(512, 2) void g2_main(
    const float* __restrict__ coords, const float* __restrict__ metric,
    const u32* __restrict__ wsW, float* __restrict__ partials) {
  __shared__ __align__(16) u32 SMEM[NW_U32];
  const int tid = threadIdx.x;

  { // stage weights: 4785 uint4 = 19140 u32
    const u32x4* src = (const u32x4*)wsW;
    u32x4* dst = (u32x4*)SMEM;
    #pragma unroll
    for (int i = 0; i < 10; ++i) {
      int idx = tid + 512 * i;
      if (idx < 4785) dst[idx] = src[idx];
    }
  }
  __syncthreads();

  const int lane = tid & 63, wv = tid >> 6;
  const int g = lane >> 4, c = lane & 15;
  const int wave_gid = blockIdx.x * 8 + wv;
  const int sbase = wave_gid * 64;
  const char* LB = (const char*)SMEM;
  const float c2v = ((const float*)SMEM)[IDX_C2];

  // ---- dets for all 4 tiles up-front (symmetric GE on lower triangle, 28 regs) ----
  float detv = 1.f, lposv = 0.f;
  {
    const float* Mg = metric + (size_t)(sbase + lane) * 49;
    float m[28];
    #pragma unroll
    for (int i = 0; i < 7; ++i)
      #pragma unroll
      for (int j = 0; j <= i; ++j)
        m[i*(i+1)/2 + j] = Mg[i*7 + j];
    float minpiv = 3.4e38f;
    #pragma unroll
    for (int k = 0; k < 7; ++k) {
      float piv = m[k*(k+1)/2 + k];
      minpiv = fminf(minpiv, piv);
      detv *= piv;
      float inv = 1.0f / piv;
      #pragma unroll
      for (int i = k + 1; i < 7; ++i) {
        float f = m[i*(i+1)/2 + k] * inv;
        #pragma unroll
        for (int j = k + 1; j <= i; ++j)
          m[i*(i+1)/2 + j] = fmaf(-f, m[j*(j+1)/2 + k], m[i*(i+1)/2 + j]);
      }
    }
    if (!(minpiv > 1e-4f)) eig7_fallback(Mg, &detv, &lposv);
  }

  float acc = 0.f;

  #pragma unroll 1
  for (int t = 0; t < TPW; ++t) {
    const int sb = sbase + t * 16;

    // ---- phase 1: z = W1^T c + b1 via MFMA; tanh; s/t frags (lane-local) ----
    u32 bc[4] = {0,0,0,0};
    if (g < 2) {
      const float* cg = coords + (size_t)(sb + c) * 7 + 4*g;
      float f0 = cg[0], f1 = cg[1], f2 = cg[2];
      float f3 = (g == 0) ? cg[3] : 1.0f;     // j==7 slot multiplies the b1 row
      bc[0] = pkrtz(f0, f1); bc[1] = pkrtz(f2, f3);
    }
    const f16x8 bfrag = frag4(bc);

    u32 sf_[4][4], tf_[4][4];
    float w2t = 0.f;
    #pragma unroll 2
    for (int mt = 0; mt < 8; ++mt) {
      u32 az[4] = {0,0,0,0};
      if (g < 2) {
        u32x2 lo = *(const u32x2*)(LB + OFF_W1ZT*4 + (16*mt + c)*16 + 8*g);
        az[0] = lo.x; az[1] = lo.y;
      }
      f32x4 zz = mfma16(frag4(az), bfrag, f32x4{0.f,0.f,0.f,0.f});
      f32x4 wb = *(const f32x4*)(LB + OFF_W2B*4 + (16*mt + 4*g)*4);
      float tt[4], ss[4];
      #pragma unroll
      for (int r = 0; r < 4; ++r) {
        float ex = __builtin_amdgcn_exp2f(zz[r] * 2.8853900817779268f); // e^{2z}
        float rc = __builtin_amdgcn_rcpf(ex + 1.0f);
        float tv = fmaf(-2.0f, rc, 1.0f);
        tt[r] = tv; ss[r] = fmaf(-tv, tv, 1.0f);
        w2t = fmaf(tv, wb[r], w2t);
      }
      const int kk = mt >> 1, u0 = 2*(mt & 1);
      tf_[kk][u0]   = pkrtz(tt[0], tt[1]);
      tf_[kk][u0+1] = pkrtz(tt[2], tt[3]);
      sf_[kk][u0]   = pkrtz(ss[0], ss[1]);
      sf_[kk][u0+1] = pkrtz(ss[2], ss[3]);
    }

    // ---- phase 2: V = Q S^T (MFMA); F2 = s . V lane-locally ----
    float F2 = 0.f;
    #pragma unroll 2
    for (int mt = 0; mt < 8; ++mt) {
      const int row = c + 16*mt;
      f32x4 a = {0.f,0.f,0.f,0.f};
      #pragma unroll
      for (int kk = 0; kk < 4; ++kk) {
        u32x4 fr = *(const u32x4*)(LB + (OFF_QP + row*68 + kk*16)*4 + g*16);
        a = mfma16(fragv(fr), frag4(sf_[kk]), a);
      }
      const int kk2 = mt >> 1, u0 = 2*(mt & 1);
      F2 = fdot2f(sf_[kk2][u0],   pkrtz(a[0], a[1]), F2);
      F2 = fdot2f(sf_[kk2][u0+1], pkrtz(a[2], a[3]), F2);
    }

    // ---- phase 3+4 fused: V2 = M2 T^T; n2 diag; u = s o (V2+w2b); G += W1 U^T ----
    float n2d = 0.f;
    f32x4 ga = {0.f,0.f,0.f,0.f};
    u32 up0 = 0, up1 = 0;
    #pragma unroll 2
    for (int mt = 0; mt < 8; ++mt) {
      const int row = c + 16*mt;
      f32x4 a = {0.f,0.f,0.f,0.f};
      #pragma unroll
      for (int kk = 0; kk < 4; ++kk) {
        u32x4 fr = *(const u32x4*)(LB + (OFF_M2P + row*68 + kk*16)*4 + g*16);
        a = mfma16(fragv(fr), frag4(tf_[kk]), a);
      }
      const int kk2 = mt >> 1, u0 = 2*(mt & 1);
      n2d = fdot2f(tf_[kk2][u0],   pkrtz(a[0], a[1]), n2d);
      n2d = fdot2f(tf_[kk2][u0+1], pkrtz(a[2], a[3]), n2d);
      f32x4 wb = *(const f32x4*)(LB + OFF_W2B*4 + (16*mt + 4*g)*4);
      float s0 = lo16f(sf_[kk2][u0]),   s1 = hi16f(sf_[kk2][u0]);
      float s2 = lo16f(sf_[kk2][u0+1]), s3 = hi16f(sf_[kk2][u0+1]);
      u32 pa = pkrtz(s0*(a[0]+wb[0]), s1*(a[1]+wb[1]));
      u32 pb = pkrtz(s2*(a[2]+wb[2]), s3*(a[3]+wb[3]));
      if ((mt & 1) == 0) {
        up0 = pa; up1 = pb;
      } else {
        const int kk = mt >> 1;
        u32 ub[4] = { up0, up1, pa, pb };
        u32x4 fr = *(const u32x4*)(LB + (OFF_W1H + c*68 + kk*16)*4 + g*16);
        ga = mfma16(fragv(fr), frag4(ub), ga);
      }
    }
    float p2g = 0.f;
    if (g == 0)      p2g = ga[0]*ga[0] + ga[1]*ga[1] + ga[2]*ga[2] + ga[3]*ga[3];
    else if (g == 1) p2g = ga[0]*ga[0] + ga[1]*ga[1] + ga[2]*ga[2];  // j = 4,5,6

    // ---- reductions over g-groups (column c fixed) ----
    F2  += __shfl_xor(F2, 16);  F2  += __shfl_xor(F2, 32);
    n2d += __shfl_xor(n2d, 16); n2d += __shfl_xor(n2d, 32);
    w2t += __shfl_xor(w2t, 16); w2t += __shfl_xor(w2t, 32);
    p2g += __shfl_xor(p2g, 16); p2g += __shfl_xor(p2g, 32);

    const float det  = __shfl(detv,  16*t + c);
    const float lpos = __shfl(lposv, 16*t + c);

    if (g == 0) {
      float n2 = n2d + 2.0f*w2t + c2v;
      float v  = sqrtf(fabsf(det) + 1e-10f);
      float nn = sqrtf(fmaxf(n2, 0.0f));
      float rr = fmaf(v, nn, 1e-8f);
      float a2 = 7.0f * v * v / (rr * rr);
      float be = v / (rr * nn + 1e-20f);
      float fac = be * (2.0f - be * n2);
      float dual = a2 * (F2 - fac * p2g);
      float dm1 = det - 1.0f, nm7 = n2 - 7.0f;
      acc += F2 + dual + dm1*dm1 + nm7*nm7 + lpos;
    }
  }

  // ---- block reduction (clobbers weight LDS; all waves done) ----
  __syncthreads();
  float* SFw = (float*)SMEM;
  SFw[tid] = acc;
  __syncthreads();
  #pragma unroll
  for (int s = 256; s > 0; s >>= 1) {
    if (tid < s) SFw[tid] += SFw[tid + s];
    __syncthreads();
  }
  if (tid == 0) partials[blockIdx.x] = SFw[0];
}

__global__ void g2_finish(const float* __restrict__ partials, float* __restrict__ out) {
  __shared__ float red[256];
  int t = threadIdx.x;
  red[t] = partials[t] + partials[t + 256];
  __syncthreads();
  #pragma unroll
  for (int s = 128; s > 0; s >>= 1) {
    if (t < s) red[t] += red[t + s];
    __syncthreads();
  }
  if (t == 0) out[0] = red[0] * (1.0f / (float)B_TOTAL);
}

extern "C" void kernel_launch(void* const* d_in, const int* in_sizes, int n_in,
                              void* d_out, int out_size, void* d_ws, size_t ws_size,
                              hipStream_t stream) {
  (void)in_sizes; (void)n_in; (void)out_size; (void)ws_size;
  const float* coords = (const float*)d_in[0];
  const float* metric = (const float*)d_in[1];
  const float* W1     = (const float*)d_in[2];
  const float* b1     = (const float*)d_in[3];
  const float* W2     = (const float*)d_in[4];
  const float* b2     = (const float*)d_in[5];
  float* out = (float*)d_out;

  u32* ws = (u32*)d_ws;
  float* partials = (float*)(ws + NW_U32);

  g2_prep<<<39, 256, 0, stream>>>(W1, b1, W2, b2, ws);
  g2_main<<<NBLK, 512, 0, stream>>>(coords, metric, ws, partials);
  g2_finish<<<1, 256, 0, stream>>>(partials, out);
}